// Round 9
// baseline (574.468 us; speedup 1.0000x reference)
//
#include <hip/hip_runtime.h>
#include <hip/hip_bf16.h>
#include <math.h>

#define BDIM 1024
#define TDIM 4096
#define BT   16384   // B*T
#define KEXPN 8
#define RRANK 64
#define KR   512     // KEXPN*RRANK
#define KC   640     // per-branch extended width: 512 prod + 8 bias + 120 pad (5*128)
#define PW   1280    // concatenated P width (2*KC)
#define KRC  1024    // concatenated xV/yW width
#define NCH  64
#define TC   64      // T per chunk (NCH*TC == TDIM)

typedef __attribute__((ext_vector_type(8))) short bf16x8;
typedef __attribute__((ext_vector_type(4))) float f32x4;

typedef __attribute__((address_space(1))) char g_char;
typedef __attribute__((address_space(3))) char l_char;

// async 16B global->LDS: per-lane global addr, wave-uniform LDS base (+lane*16 by HW)
__device__ __forceinline__ void gload16(const short* g, short* lds_base_uniform) {
  __builtin_amdgcn_global_load_lds((const g_char*)(const char*)g,
                                   (l_char*)(char*)lds_base_uniform, 16, 0, 0);
}

// ---------------- elementwise conversion f32 -> bf16 (vectorized x4) ----------------
__global__ __launch_bounds__(256) void cvt_bf16_kernel(const float* __restrict__ in,
    __hip_bfloat16* __restrict__ out, long n4) {
  long id = (long)blockIdx.x * 256 + threadIdx.x;
  if (id >= n4) return;
  f32x4 v = ((const f32x4*)in)[id];
  long i = id * 4;
  out[i + 0] = __float2bfloat16(v[0]);
  out[i + 1] = __float2bfloat16(v[1]);
  out[i + 2] = __float2bfloat16(v[2]);
  out[i + 3] = __float2bfloat16(v[3]);
}

// ---------------- transpose-pack: out[e][d] = in[d][e], f32 -> bf16, D x D ----------------
__global__ __launch_bounds__(256) void transpose_pack_kernel(const float* __restrict__ in,
    __hip_bfloat16* __restrict__ out) {
  int id = blockIdx.x * 256 + threadIdx.x;   // 0 .. D*D
  if (id >= BDIM * BDIM) return;
  int d = id & (BDIM - 1);
  int e = id >> 10;
  out[(size_t)e * BDIM + d] = __float2bfloat16(in[(size_t)d * BDIM + e]);
}

// ---------------- pack V (K,D,R) -> Vmat[(k*64+r)][d] bf16 ----------------
__global__ __launch_bounds__(256) void pack_vmat_kernel(const float* __restrict__ V,
    __hip_bfloat16* __restrict__ out) {
  int id = blockIdx.x * 256 + threadIdx.x;     // 0 .. KR*BDIM
  if (id >= KR * BDIM) return;
  int d = id & (BDIM - 1);
  int kr = id >> 10;
  int k = kr >> 6, r = kr & 63;
  out[(size_t)kr * BDIM + d] = __float2bfloat16(V[((size_t)k * BDIM + d) * RRANK + r]);
}

// ---------------- pack U (K,D,R)+b (K,D) -> utT[c][e], c in [0,640) ----------------
__global__ __launch_bounds__(256) void pack_utT_kernel(const float* __restrict__ U,
    const float* __restrict__ bvec, __hip_bfloat16* __restrict__ out) {
  int id = blockIdx.x * 256 + threadIdx.x;     // 0 .. KC*BDIM
  if (id >= KC * BDIM) return;
  int e = id & (BDIM - 1);
  int c = id >> 10;
  float v = 0.0f;
  if (c < KR) {
    int k = c >> 6, r = c & 63;
    v = U[((size_t)k * BDIM + e) * RRANK + r];
  } else if (c < KR + KEXPN) {
    v = bvec[(size_t)(c - KR) * BDIM + e];
  }
  out[(size_t)c * BDIM + e] = __float2bfloat16(v);
}

// ================= 128^2 2-phase engine (small folds only) =================
template<int EPI>
__global__ __launch_bounds__(256) void gemm_nt(const __hip_bfloat16* __restrict__ A,
    const __hip_bfloat16* __restrict__ B, void* __restrict__ Cv, void* __restrict__ Cv2,
    int csplit, int ldc, int ldc2, const float* __restrict__ bias, int M, int N, int Kd) {
  __shared__ __align__(16) short Als[2][128 * 32];
  __shared__ __align__(16) short Bls[2][128 * 32];
  int nbx = gridDim.x;
  int nwg = nbx * gridDim.y;
  int bx = blockIdx.x, by = blockIdx.y;
  if ((nwg & 7) == 0) {
    int orig = by * nbx + bx;
    int cpx = nwg >> 3;
    int id = (orig & 7) * cpx + (orig >> 3);
    bx = id % nbx; by = id / nbx;
  }
  const short* As = (const short*)A;
  const short* Bs = (const short*)B;
  const int t  = threadIdx.x;
  const int w  = t >> 6;
  const int l  = t & 63;
  const int lr = l & 15;
  const int lk = l >> 4;
  const int wr = w >> 1;
  const int wc = w & 1;
  const int row0 = by * 128;
  const int col0 = bx * 128;
  const int srow = w * 16 + (l >> 2);
  const int scol = (l & 3) * 8;
  const short* ag0 = As + (size_t)(row0 + srow) * Kd + scol;
  const short* ag1 = As + (size_t)(row0 + 64 + srow) * Kd + scol;
  const short* bg0 = Bs + (size_t)(col0 + srow) * Kd + scol;
  const short* bg1 = Bs + (size_t)(col0 + 64 + srow) * Kd + scol;
  f32x4 acc[4][4] = {};
  const int nt = Kd / 32;
  auto stage = [&](int kt, int buf) {
    int k0 = kt * 32;
    gload16(ag0 + k0, &Als[buf][w * 512]);
    gload16(ag1 + k0, &Als[buf][2048 + w * 512]);
    gload16(bg0 + k0, &Bls[buf][w * 512]);
    gload16(bg1 + k0, &Bls[buf][2048 + w * 512]);
  };
  stage(0, 0);
  __syncthreads();
  int cur = 0;
  for (int kt = 0; kt < nt; ++kt) {
    if (kt + 1 < nt) stage(kt + 1, cur ^ 1);
    bf16x8 af[4], bfr[4];
    #pragma unroll
    for (int i = 0; i < 4; i++)
      af[i] = *(const bf16x8*)&Als[cur][(wr * 64 + i * 16 + lr) * 32 + lk * 8];
    #pragma unroll
    for (int j = 0; j < 4; j++)
      bfr[j] = *(const bf16x8*)&Bls[cur][(wc * 64 + j * 16 + lr) * 32 + lk * 8];
    #pragma unroll
    for (int i = 0; i < 4; i++)
      #pragma unroll
      for (int j = 0; j < 4; j++)
        acc[i][j] = __builtin_amdgcn_mfma_f32_16x16x32_bf16(af[i], bfr[j], acc[i][j], 0, 0, 0);
    __syncthreads();
    cur ^= 1;
  }
  #pragma unroll
  for (int i = 0; i < 4; i++)
    #pragma unroll
    for (int j = 0; j < 4; j++)
      #pragma unroll
      for (int g = 0; g < 4; g++) {
        int r = row0 + wr * 64 + i * 16 + lk * 4 + g;
        int c = col0 + wc * 64 + j * 16 + lr;
        float v = acc[i][j][g];
        void* dst = Cv;
        int cc = c, ld = ldc;
        if (c >= csplit) { dst = Cv2; cc = c - csplit; ld = ldc2; }
        size_t idx = (size_t)r * ld + cc;
        if (EPI == 0)      ((float*)dst)[idx] = v;
        else if (EPI == 1) ((__hip_bfloat16*)dst)[idx] = __float2bfloat16(v);
        else if (EPI == 2) {
          float xv = v + bias[cc];
          float gl = 0.5f * xv * (1.0f + erff(xv * 0.70710678118654752f));
          ((__hip_bfloat16*)dst)[idx] = __float2bfloat16(gl);
        } else {
          float s = 1.0f / (float)((r & (TDIM - 1)) + 1);
          ((float*)dst)[idx] = v * s;
        }
      }
}

// ================= 256^2 pipelined engine (big GEMMs) — R6 schedule + LDS epilogue =================
// BM=BN=256, BK=32, 8 waves (2M x 4N), 4-deep LDS ring (128 KiB), counted vmcnt(8),
// 2 phases/iter {reads | stage | barrier | setprio 16 MFMA | barrier}, end-of-iter counted wait.
// Epilogue: wave-private 16 KB LDS region re-layout -> 16 B/lane coalesced global stores.
template<int EPI>
__global__ __launch_bounds__(512, 2) void gemm_nt_256(const __hip_bfloat16* __restrict__ A,
    const __hip_bfloat16* __restrict__ B, void* __restrict__ Cv, void* __restrict__ Cv2,
    int csplit, int ldc, int ldc2, const float* __restrict__ bias, int M, int N, int Kd) {
  __shared__ __align__(16) short Als[4][256 * 32];   // 64 KB
  __shared__ __align__(16) short Bls[4][256 * 32];   // 64 KB

  int nbx = gridDim.x;
  int nwg = nbx * gridDim.y;
  int bx = blockIdx.x, by = blockIdx.y;
  if ((nwg & 7) == 0) {
    int orig = by * nbx + bx;
    int cpx = nwg >> 3;
    int id = (orig & 7) * cpx + (orig >> 3);
    bx = id % nbx; by = id / nbx;
  }
  const short* As = (const short*)A;
  const short* Bs = (const short*)B;
  const int t  = threadIdx.x;      // 0..511
  const int w  = t >> 6;           // 0..7
  const int l  = t & 63;
  const int lr = l & 15;
  const int lk = l >> 4;
  const int wr = w >> 2;           // 0..1 (M half)
  const int wc = w & 3;            // 0..3 (N quarter)
  const int row0 = by * 256;
  const int col0 = bx * 256;

  // staging map: thread t covers LDS linear bytes [c*8192 + t*16), c=chunk(0..1)
  const int srow  = t >> 2;                       // 0..127
  const int sslot = (t & 3) ^ ((srow >> 1) & 3);  // same for row and row+128
  const short* agA0 = As + (size_t)(row0 + srow) * Kd + sslot * 8;
  const short* agA1 = As + (size_t)(row0 + 128 + srow) * Kd + sslot * 8;
  const short* bgB0 = Bs + (size_t)(col0 + srow) * Kd + sslot * 8;
  const short* bgB1 = Bs + (size_t)(col0 + 128 + srow) * Kd + sslot * 8;

  auto stage2A = [&](int kt3) {
    int k0 = kt3 << 5;
    short* base = &Als[kt3 & 3][0];
    gload16(agA0 + k0, base + w * 512);
    gload16(agA1 + k0, base + 4096 + w * 512);
  };
  auto stage2B = [&](int kt3) {
    int k0 = kt3 << 5;
    short* base = &Bls[kt3 & 3][0];
    gload16(bgB0 + k0, base + w * 512);
    gload16(bgB1 + k0, base + 4096 + w * 512);
  };

  // fragment LDS offsets (shorts), swizzled; constant across iterations
  int aoff[8], boff[4];
  #pragma unroll
  for (int mf = 0; mf < 8; ++mf) {
    int r = wr * 128 + mf * 16 + lr;
    aoff[mf] = r * 32 + ((lk ^ ((r >> 1) & 3)) << 3);
  }
  #pragma unroll
  for (int nf = 0; nf < 4; ++nf) {
    int r = wc * 64 + nf * 16 + lr;
    boff[nf] = r * 32 + ((lk ^ ((r >> 1) & 3)) << 3);
  }

  f32x4 acc[8][4] = {};
  const int NT = Kd >> 5;

  // prologue: stage tiles 0..2, wait tile 0 (8 loads = tiles 1,2 stay in flight)
  stage2A(0); stage2B(0);
  stage2A(1); stage2B(1);
  stage2A(2); stage2B(2);
  asm volatile("s_waitcnt vmcnt(8)" ::: "memory");
  __builtin_amdgcn_sched_barrier(0);
  __builtin_amdgcn_s_barrier();

  for (int kt = 0; kt < NT; ++kt) {
    const short* Ab = &Als[kt & 3][0];
    const short* Bb = &Bls[kt & 3][0];
    const bool st = (kt + 3 < NT);
    // phase 0: A-frags 0..3 + all B-frags; stage A of kt+3; 16 MFMA
    bf16x8 af[4], bfr[4];
    #pragma unroll
    for (int mf = 0; mf < 4; ++mf) af[mf] = *(const bf16x8*)&Ab[aoff[mf]];
    #pragma unroll
    for (int nf = 0; nf < 4; ++nf) bfr[nf] = *(const bf16x8*)&Bb[boff[nf]];
    if (st) stage2A(kt + 3);
    __builtin_amdgcn_s_barrier();
    __builtin_amdgcn_s_setprio(1);
    #pragma unroll
    for (int mf = 0; mf < 4; ++mf)
      #pragma unroll
      for (int nf = 0; nf < 4; ++nf)
        acc[mf][nf] = __builtin_amdgcn_mfma_f32_16x16x32_bf16(af[mf], bfr[nf], acc[mf][nf], 0, 0, 0);
    __builtin_amdgcn_s_setprio(0);
    __builtin_amdgcn_s_barrier();
    // phase 1: A-frags 4..7 (B reused in regs); stage B of kt+3; 16 MFMA
    bf16x8 ag[4];
    #pragma unroll
    for (int mf = 0; mf < 4; ++mf) ag[mf] = *(const bf16x8*)&Ab[aoff[4 + mf]];
    if (st) stage2B(kt + 3);
    __builtin_amdgcn_s_barrier();
    __builtin_amdgcn_s_setprio(1);
    #pragma unroll
    for (int mf = 0; mf < 4; ++mf)
      #pragma unroll
      for (int nf = 0; nf < 4; ++nf)
        acc[4 + mf][nf] = __builtin_amdgcn_mfma_f32_16x16x32_bf16(ag[mf], bfr[nf], acc[4 + mf][nf], 0, 0, 0);
    __builtin_amdgcn_s_setprio(0);
    // counted end-of-iteration wait: tile kt+1 fully landed; never drain below prefetch depth
    if (kt + 3 < NT)      { asm volatile("s_waitcnt vmcnt(8)" ::: "memory"); }
    else if (kt + 2 < NT) { asm volatile("s_waitcnt vmcnt(4)" ::: "memory"); }
    else if (kt + 1 < NT) { asm volatile("s_waitcnt vmcnt(0)" ::: "memory"); }
    __builtin_amdgcn_sched_barrier(0);
    __builtin_amdgcn_s_barrier();
  }

  // ---- epilogue: wave-private LDS re-layout -> coalesced 16 B/lane stores ----
  // After the loop's final barrier all LDS reads and all DMA writes have retired
  // (tail waits drained vmcnt to 0 by kt==NT-2). Each wave owns a 16 KB region.
  short* reg = (w < 4) ? &Als[w][0] : &Bls[w - 4][0];

  if (EPI == 1 || EPI == 2) {
    #pragma unroll
    for (int mf = 0; mf < 8; ++mf)
      #pragma unroll
      for (int nf = 0; nf < 4; ++nf)
        #pragma unroll
        for (int g = 0; g < 4; ++g) {
          int rl = mf * 16 + lk * 4 + g;     // 0..127
          int cl = nf * 16 + lr;             // 0..63
          float v = acc[mf][nf][g];
          if (EPI == 2) {
            int cg = col0 + wc * 64 + cl;
            int cc = (cg >= csplit) ? cg - csplit : cg;
            float xv = v + bias[cc];
            v = 0.5f * xv * (1.0f + erff(xv * 0.70710678118654752f));
          }
          // slot-XOR swizzle: slots of 8 bf16 (16 B), slot' = slot ^ (rl&7) -> 2-way max
          ((__hip_bfloat16*)reg)[rl * 64 + (((cl >> 3) ^ (rl & 7)) << 3) + (cl & 7)] =
              __float2bfloat16(v);
        }
    #pragma unroll
    for (int i = 0; i < 16; ++i) {
      int rl = (l >> 3) + i * 8;
      int sl = l & 7;
      bf16x8 vv = *(const bf16x8*)&reg[rl * 64 + ((sl ^ (rl & 7)) << 3)];
      int rg = row0 + wr * 128 + rl;
      int cg = col0 + wc * 64 + sl * 8;
      void* dst = Cv; int cc = cg, ld = ldc;
      if (cg >= csplit) { dst = Cv2; cc = cg - csplit; ld = ldc2; }
      *(bf16x8*)((short*)dst + (size_t)rg * ld + cc) = vv;
    }
  } else {
    // f32 EPIs (0 and 4): two 32-column passes (16 KB each), slots of 4 f32 (16 B)
    float* regf = (float*)reg;
    #pragma unroll
    for (int half = 0; half < 2; ++half) {
      #pragma unroll
      for (int mf = 0; mf < 8; ++mf)
        #pragma unroll
        for (int nfh = 0; nfh < 2; ++nfh)
          #pragma unroll
          for (int g = 0; g < 4; ++g) {
            int nf = half * 2 + nfh;
            int rl = mf * 16 + lk * 4 + g;
            int cl = nfh * 16 + lr;          // 0..31
            float v = acc[mf][nf][g];
            if (EPI == 4) {
              int rg = row0 + wr * 128 + rl;
              v *= 1.0f / (float)((rg & (TDIM - 1)) + 1);
            }
            regf[rl * 32 + (((cl >> 2) ^ (rl & 7)) << 2) + (cl & 3)] = v;
          }
      #pragma unroll
      for (int i = 0; i < 16; ++i) {
        int rl = (l >> 3) + i * 8;
        int sl = l & 7;
        f32x4 vv = *(const f32x4*)&regf[rl * 32 + ((sl ^ (rl & 7)) << 2)];
        int rg = row0 + wr * 128 + rl;
        int cg = col0 + wc * 64 + half * 32 + sl * 4;
        void* dst = Cv; int cc = cg, ld = ldc;
        if (cg >= csplit) { dst = Cv2; cc = cg - csplit; ld = ldc2; }
        *(f32x4*)((float*)dst + (size_t)rg * ld + cc) = vv;
      }
      // wave-private region; per-wave DS ops are in-order -> no barrier between passes
    }
  }
}

// ---------------- dual router: one launch covers Hf (y=0) and Hi (y=1) ----------------
__global__ __launch_bounds__(256) void router_kernel(const __hip_bfloat16* __restrict__ Hf,
    const __hip_bfloat16* __restrict__ Hi,
    const float* __restrict__ w2, const float* __restrict__ b2,
    const float* __restrict__ ebias, float* __restrict__ wgt_f, float* __restrict__ wgt_i) {
  const __hip_bfloat16* H = blockIdx.y ? Hi : Hf;
  float* wgt = blockIdx.y ? wgt_i : wgt_f;
  int wv = threadIdx.x >> 6;
  int l  = threadIdx.x & 63;
  int row = blockIdx.x * 4 + wv;
  if (row >= BT) return;
  float acc[KEXPN] = {};
  for (int i = 0; i < BDIM / 64; i++) {
    int h = i * 64 + l;
    float hv = __bfloat162float(H[(size_t)row * BDIM + h]);
    #pragma unroll
    for (int k = 0; k < KEXPN; k++) acc[k] += hv * w2[k * BDIM + h];
  }
  #pragma unroll
  for (int k = 0; k < KEXPN; k++)
    for (int off = 32; off; off >>= 1) acc[k] += __shfl_down(acc[k], off);
  if (l == 0) {
    float lg[KEXPN];
    float mx = -1e30f;
    #pragma unroll
    for (int k = 0; k < KEXPN; k++) { lg[k] = acc[k] + b2[k] + ebias[k]; mx = fmaxf(mx, lg[k]); }
    float s = 0.0f;
    #pragma unroll
    for (int k = 0; k < KEXPN; k++) { lg[k] = expf(lg[k] - mx); s += lg[k]; }
    float inv = 1.0f / s;
    #pragma unroll
    for (int k = 0; k < KEXPN; k++) wgt[(size_t)row * KEXPN + k] = lg[k] * inv;
  }
}

// ---------------- cumsum phase 1: per-chunk sums (yW is bf16) ----------------
__global__ __launch_bounds__(1024) void chunksum_kernel(const __hip_bfloat16* __restrict__ yW,
    float* __restrict__ S) {
  int j  = threadIdx.x;
  int ch = blockIdx.x;
  int b  = blockIdx.y;
  size_t base = ((size_t)b * TDIM + ch * TC) * KRC + j;
  float s = 0.0f;
  for (int t = 0; t < TC; t++) s += __bfloat162float(yW[base + (size_t)t * KRC]);
  S[((size_t)b * NCH + ch) * KRC + j] = s;
}

// ---------------- cumsum phase 2: exclusive scan of chunk sums (in place) ----------------
__global__ __launch_bounds__(1024) void scan_chunks_kernel(float* __restrict__ S) {
  int j = threadIdx.x;
  int b = blockIdx.x;
  float run = 0.0f;
  for (int ch = 0; ch < NCH; ch++) {
    size_t i = ((size_t)b * NCH + ch) * KRC + j;
    float v = S[i];
    S[i] = run;
    run += v;
  }
}

// ---------------- cumsum phase 3 + combine both branches -> Pcat (+ ext cols fused) ----------------
__global__ __launch_bounds__(1024) void combine_kernel(const __hip_bfloat16* __restrict__ yW,
    const float* __restrict__ S, const __hip_bfloat16* __restrict__ xV,
    const float* __restrict__ wf, const float* __restrict__ wi,
    const float* __restrict__ alphaPtr, __hip_bfloat16* __restrict__ P) {
  int j  = threadIdx.x;
  int ch = blockIdx.x;
  int b  = blockIdx.y;
  float alpha = alphaPtr[0];
  float scale = (j < KR) ? 1.0f : alpha;
  const float* wgt = (j < KR) ? wf : wi;
  int k = (j & (KR - 1)) >> 6;
  int pcol = (j < KR) ? j : j + 128;
  float run = S[((size_t)b * NCH + ch) * KRC + j];
  for (int t0 = 0; t0 < TC; t0++) {
    size_t row = (size_t)b * TDIM + ch * TC + t0;
    run += __bfloat162float(yW[row * KRC + j]);
    float p = __bfloat162float(xV[row * KRC + j]) * run * wgt[row * KEXPN + k] * scale;
    P[row * PW + pcol] = __float2bfloat16(p);
  }
  // fused ext-column fill: threads 0..255 write the 2x128 extension columns
  if (j < 256) {
    int half = j >> 7, jj = j & 127;
    int col = half ? (KC + KR + jj) : (KR + jj);
    const float* wg = half ? wi : wf;
    float sc = half ? alpha : 1.0f;
    for (int t0 = 0; t0 < TC; t0++) {
      size_t row = (size_t)b * TDIM + ch * TC + t0;
      float v = (jj < KEXPN) ? wg[row * KEXPN + jj] * sc : 0.0f;
      P[row * PW + col] = __float2bfloat16(v);
    }
  }
}

// ---------------- sentinel ----------------
__global__ __launch_bounds__(256) void fill_kernel(float* __restrict__ out, long n, float val) {
  long id = (long)blockIdx.x * 256 + threadIdx.x;
  if (id < n) out[id] = val;
}

extern "C" void kernel_launch(void* const* d_in, const int* in_sizes, int n_in,
                              void* d_out, int out_size, void* d_ws, size_t ws_size,
                              hipStream_t stream) {
  const float* x        = (const float*)d_in[0];
  const float* W_Q      = (const float*)d_in[1];
  const float* W_K      = (const float*)d_in[2];
  const float* W_O      = (const float*)d_in[3];
  const float* W_inv    = (const float*)d_in[4];
  const float* V_fwd    = (const float*)d_in[5];
  const float* W_fwd    = (const float*)d_in[6];
  const float* U_fwd    = (const float*)d_in[7];
  const float* b_fwd    = (const float*)d_in[8];
  const float* V_inv    = (const float*)d_in[9];
  const float* W_inv_e  = (const float*)d_in[10];
  const float* U_inv    = (const float*)d_in[11];
  const float* b_inv    = (const float*)d_in[12];
  const float* rw1      = (const float*)d_in[13];
  const float* rb1      = (const float*)d_in[14];
  const float* rw2      = (const float*)d_in[15];
  const float* rb2      = (const float*)d_in[16];
  const float* alphaPtr = (const float*)d_in[17];
  const float* ebias    = (const float*)d_in[18];

  char* ws = (char*)d_ws;
  size_t off = 0;
  auto alloc = [&](size_t sz) -> void* {
    void* p = ws + off;
    off += (sz + 255) & ~(size_t)255;
    return p;
  };

  void* wqk   = alloc((size_t)2 * BDIM * BDIM * 2); // [W_Q rows | W_K rows]
  void* w1p   = alloc((size_t)2 * BDIM * BDIM * 2); // [w1 rows | w1i rows]
  void* wo    = alloc((size_t)BDIM * BDIM * 2);
  void* winvT = alloc((size_t)BDIM * BDIM * 2);
  void* vmq   = alloc((size_t)KRC * BDIM * 2);      // rows 0-511 vm_f, 512-1023 Gq
  void* wmG   = alloc((size_t)KRC * BDIM * 2);      // rows 0-511 wm_f, 512-1023 Gk
  void* vm_ie = alloc((size_t)KR * BDIM * 2);
  void* vm_i  = alloc((size_t)KR * BDIM * 2);
  void* utTf  = alloc((size_t)KC * BDIM * 2);
  void* utTi  = alloc((size_t)KC * BDIM * 2);
  void* Mcat  = alloc((size_t)BDIM * PW * 2);
  void* wgt_f = alloc((size_t)BT * KEXPN * 4);
  void* wgt_i = alloc((size_t)BT * KEXPN * 4);
  void* S     = alloc((size_t)4 * NCH * KRC * 4);
  void* s_Q   = alloc((size_t)BT * BDIM * 2);
  void* s_K   = alloc((size_t)BT * BDIM * 2);
  void* s_x   = alloc((size_t)BT * BDIM * 2);
  void* s_yW  = alloc((size_t)BT * KRC * 2);        // bf16: Hi (early), then yWcat
  void* Hf    = s_x;
  void* Hi    = s_yW;
  void* xVcat = s_x;
  void* Pcat  = s_Q;

  if (off > ws_size) {
    fill_kernel<<<dim3((unsigned)((out_size + 255) / 256)), 256, 0, stream>>>(
        (float*)d_out, (long)out_size, (float)(off >> 20));
    return;
  }

  __hip_bfloat16* wq  = (__hip_bfloat16*)wqk;
  __hip_bfloat16* wk  = wq + (size_t)BDIM * BDIM;
  __hip_bfloat16* w1  = (__hip_bfloat16*)w1p;
  __hip_bfloat16* w1i = w1 + (size_t)BDIM * BDIM;
  __hip_bfloat16* Gq  = (__hip_bfloat16*)vmq + (size_t)KR * BDIM;
  __hip_bfloat16* Gk  = (__hip_bfloat16*)wmG + (size_t)KR * BDIM;

  auto cvt = [&](const float* in, void* out, long n) {
    long n4 = n / 4;
    cvt_bf16_kernel<<<dim3((unsigned)((n4 + 255) / 256)), dim3(256), 0, stream>>>(
        in, (__hip_bfloat16*)out, n4);
  };
  // 128^2 engine (folds)
  auto gemm2s = [&](const void* A, const void* Bm, void* C, void* C2, int csplit,
                    int ldc, int ldc2, int M, int N, int Kd, int epi, const float* bias) {
    dim3 g(N / 128, M / 128);
    if (epi == 0)      gemm_nt<0><<<g, 256, 0, stream>>>((const __hip_bfloat16*)A, (const __hip_bfloat16*)Bm, C, C2, csplit, ldc, ldc2, bias, M, N, Kd);
    else if (epi == 1) gemm_nt<1><<<g, 256, 0, stream>>>((const __hip_bfloat16*)A, (const __hip_bfloat16*)Bm, C, C2, csplit, ldc, ldc2, bias, M, N, Kd);
    else if (epi == 2) gemm_nt<2><<<g, 256, 0, stream>>>((const __hip_bfloat16*)A, (const __hip_bfloat16*)Bm, C, C2, csplit, ldc, ldc2, bias, M, N, Kd);
    else               gemm_nt<4><<<g, 256, 0, stream>>>((const __hip_bfloat16*)A, (const __hip_bfloat16*)Bm, C, C2, csplit, ldc, ldc2, bias, M, N, Kd);
  };
  auto gemms = [&](const void* A, const void* Bm, void* C, int M, int N, int Kd,
                   int epi, const float* bias) {
    gemm2s(A, Bm, C, C, N, N, N, M, N, Kd, epi, bias);
  };
  // 256^2 pipelined engine (big GEMMs; M,N multiples of 256, K multiple of 32, K/32 >= 4)
  auto gemm2b = [&](const void* A, const void* Bm, void* C, void* C2, int csplit,
                    int ldc, int ldc2, int M, int N, int Kd, int epi, const float* bias) {
    dim3 g(N / 256, M / 256);
    if (epi == 0)      gemm_nt_256<0><<<g, 512, 0, stream>>>((const __hip_bfloat16*)A, (const __hip_bfloat16*)Bm, C, C2, csplit, ldc, ldc2, bias, M, N, Kd);
    else if (epi == 1) gemm_nt_256<1><<<g, 512, 0, stream>>>((const __hip_bfloat16*)A, (const __hip_bfloat16*)Bm, C, C2, csplit, ldc, ldc2, bias, M, N, Kd);
    else if (epi == 2) gemm_nt_256<2><<<g, 512, 0, stream>>>((const __hip_bfloat16*)A, (const __hip_bfloat16*)Bm, C, C2, csplit, ldc, ldc2, bias, M, N, Kd);
    else               gemm_nt_256<4><<<g, 512, 0, stream>>>((const __hip_bfloat16*)A, (const __hip_bfloat16*)Bm, C, C2, csplit, ldc, ldc2, bias, M, N, Kd);
  };
  auto gemmb = [&](const void* A, const void* Bm, void* C, int M, int N, int Kd,
                   int epi, const float* bias) {
    gemm2b(A, Bm, C, C, N, N, N, M, N, Kd, epi, bias);
  };

  // ---- conversions & packing ----
  cvt(x,   s_x, (long)BT * BDIM);
  cvt(W_Q, wq,  (long)BDIM * BDIM);
  cvt(W_K, wk,  (long)BDIM * BDIM);
  cvt(W_O, wo,  (long)BDIM * BDIM);
  cvt(rw1, w1,  (long)BDIM * BDIM);
  {
    dim3 gt((BDIM * BDIM + 255) / 256);
    transpose_pack_kernel<<<gt, 256, 0, stream>>>(W_inv, (__hip_bfloat16*)winvT);
    dim3 g((KR * BDIM + 255) / 256);
    pack_vmat_kernel<<<g, 256, 0, stream>>>(V_fwd,   (__hip_bfloat16*)vmq);
    pack_vmat_kernel<<<g, 256, 0, stream>>>(W_fwd,   (__hip_bfloat16*)wmG);
    pack_vmat_kernel<<<g, 256, 0, stream>>>(W_inv_e, (__hip_bfloat16*)vm_ie);
    pack_vmat_kernel<<<g, 256, 0, stream>>>(V_inv,   (__hip_bfloat16*)vm_i);
    dim3 gu((KC * BDIM + 255) / 256);
    pack_utT_kernel<<<gu, 256, 0, stream>>>(U_fwd, b_fwd, (__hip_bfloat16*)utTf);
    pack_utT_kernel<<<gu, 256, 0, stream>>>(U_inv, b_inv, (__hip_bfloat16*)utTi);
  }

  // ---- weight folds (128^2 engine) ----
  gemms(w1,    winvT, w1i, BDIM, BDIM, BDIM, 1, nullptr);
  gemms(vm_ie, winvT, Gq,  KR,   BDIM, BDIM, 1, nullptr);
  gemms(vm_i,  winvT, Gk,  KR,   BDIM, BDIM, 1, nullptr);
  gemm2s(wo, utTf, Mcat, Mcat, KC, PW, PW, BDIM, KC, BDIM, 1, nullptr);
  gemm2s(wo, utTi, (__hip_bfloat16*)Mcat + KC, (__hip_bfloat16*)Mcat + KC,
         KC, PW, PW, BDIM, KC, BDIM, 1, nullptr);

  // ---- fused Q|K projection ----
  gemm2b(s_x, wqk, s_Q, s_K, BDIM, BDIM, BDIM, BT, 2 * BDIM, BDIM, 1, nullptr);

  // ---- fused H + dual router ----
  gemm2b(s_Q, w1p, Hf, Hi, BDIM, BDIM, BDIM, BT, 2 * BDIM, BDIM, 2, rb1);
  router_kernel<<<dim3(BT / 4, 2), 256, 0, stream>>>((const __hip_bfloat16*)Hf,
      (const __hip_bfloat16*)Hi, rw2, rb2, ebias, (float*)wgt_f, (float*)wgt_i);

  // ---- fused branch GEMMs (xVcat bf16 overlays Hf; yWcat bf16) ----
  gemmb(s_Q, vmq, xVcat, BT, KRC, BDIM, 1, nullptr);
  gemmb(s_K, wmG, s_yW,  BT, KRC, BDIM, 1, nullptr);

  // ---- causal cumsum + combine into Pcat (ext cols fused) ----
  dim3 gch(NCH, 4);
  chunksum_kernel<<<gch, 1024, 0, stream>>>((const __hip_bfloat16*)s_yW, (float*)S);
  scan_chunks_kernel<<<dim3(4), 1024, 0, stream>>>((float*)S);
  combine_kernel<<<gch, 1024, 0, stream>>>((const __hip_bfloat16*)s_yW, (const float*)S,
      (const __hip_bfloat16*)xVcat, (const float*)wgt_f, (const float*)wgt_i,
      alphaPtr, (__hip_bfloat16*)Pcat);

  // ---- single output GEMM: out = diag(1/n) * Pcat @ Mcat^T ----
  gemmb(Pcat, Mcat, d_out, BT, BDIM, PW, 4, nullptr);
}

// Round 10
// 553.634 us; speedup vs baseline: 1.0376x; 1.0376x over previous
//
#include <hip/hip_runtime.h>
#include <hip/hip_bf16.h>
#include <math.h>

#define BDIM 1024
#define TDIM 4096
#define BT   16384   // B*T
#define KEXPN 8
#define RRANK 64
#define KR   512     // KEXPN*RRANK
#define KC   640     // per-branch extended width: 512 prod + 8 bias + 120 pad (5*128)
#define PW   1280    // concatenated P width (2*KC)
#define KRC  1024    // concatenated xV/yW width
#define NCH  64
#define TC   64      // T per chunk (NCH*TC == TDIM)

typedef __attribute__((ext_vector_type(8))) short bf16x8;
typedef __attribute__((ext_vector_type(4))) float f32x4;

typedef __attribute__((address_space(1))) char g_char;
typedef __attribute__((address_space(3))) char l_char;

// async 16B global->LDS: per-lane global addr, wave-uniform LDS base (+lane*16 by HW)
__device__ __forceinline__ void gload16(const short* g, short* lds_base_uniform) {
  __builtin_amdgcn_global_load_lds((const g_char*)(const char*)g,
                                   (l_char*)(char*)lds_base_uniform, 16, 0, 0);
}

// ---------------- elementwise conversion f32 -> bf16 (vectorized x4) ----------------
__global__ __launch_bounds__(256) void cvt_bf16_kernel(const float* __restrict__ in,
    __hip_bfloat16* __restrict__ out, long n4) {
  long id = (long)blockIdx.x * 256 + threadIdx.x;
  if (id >= n4) return;
  f32x4 v = ((const f32x4*)in)[id];
  long i = id * 4;
  out[i + 0] = __float2bfloat16(v[0]);
  out[i + 1] = __float2bfloat16(v[1]);
  out[i + 2] = __float2bfloat16(v[2]);
  out[i + 3] = __float2bfloat16(v[3]);
}

// ---------------- transpose-pack: out[e][d] = in[d][e], f32 -> bf16, D x D ----------------
__global__ __launch_bounds__(256) void transpose_pack_kernel(const float* __restrict__ in,
    __hip_bfloat16* __restrict__ out) {
  int id = blockIdx.x * 256 + threadIdx.x;   // 0 .. D*D
  if (id >= BDIM * BDIM) return;
  int d = id & (BDIM - 1);
  int e = id >> 10;
  out[(size_t)e * BDIM + d] = __float2bfloat16(in[(size_t)d * BDIM + e]);
}

// ---------------- pack V (K,D,R) -> Vmat[(k*64+r)][d] bf16 ----------------
__global__ __launch_bounds__(256) void pack_vmat_kernel(const float* __restrict__ V,
    __hip_bfloat16* __restrict__ out) {
  int id = blockIdx.x * 256 + threadIdx.x;     // 0 .. KR*BDIM
  if (id >= KR * BDIM) return;
  int d = id & (BDIM - 1);
  int kr = id >> 10;
  int k = kr >> 6, r = kr & 63;
  out[(size_t)kr * BDIM + d] = __float2bfloat16(V[((size_t)k * BDIM + d) * RRANK + r]);
}

// ---------------- pack U (K,D,R)+b (K,D) -> utT[c][e], c in [0,640) ----------------
__global__ __launch_bounds__(256) void pack_utT_kernel(const float* __restrict__ U,
    const float* __restrict__ bvec, __hip_bfloat16* __restrict__ out) {
  int id = blockIdx.x * 256 + threadIdx.x;     // 0 .. KC*BDIM
  if (id >= KC * BDIM) return;
  int e = id & (BDIM - 1);
  int c = id >> 10;
  float v = 0.0f;
  if (c < KR) {
    int k = c >> 6, r = c & 63;
    v = U[((size_t)k * BDIM + e) * RRANK + r];
  } else if (c < KR + KEXPN) {
    v = bvec[(size_t)(c - KR) * BDIM + e];
  }
  out[(size_t)c * BDIM + e] = __float2bfloat16(v);
}

// ================= 128^2 2-phase engine (small folds only) =================
template<int EPI>
__global__ __launch_bounds__(256) void gemm_nt(const __hip_bfloat16* __restrict__ A,
    const __hip_bfloat16* __restrict__ B, void* __restrict__ Cv, void* __restrict__ Cv2,
    int csplit, int ldc, int ldc2, const float* __restrict__ bias, int M, int N, int Kd) {
  __shared__ __align__(16) short Als[2][128 * 32];
  __shared__ __align__(16) short Bls[2][128 * 32];
  int nbx = gridDim.x;
  int nwg = nbx * gridDim.y;
  int bx = blockIdx.x, by = blockIdx.y;
  if ((nwg & 7) == 0) {
    int orig = by * nbx + bx;
    int cpx = nwg >> 3;
    int id = (orig & 7) * cpx + (orig >> 3);
    bx = id % nbx; by = id / nbx;
  }
  const short* As = (const short*)A;
  const short* Bs = (const short*)B;
  const int t  = threadIdx.x;
  const int w  = t >> 6;
  const int l  = t & 63;
  const int lr = l & 15;
  const int lk = l >> 4;
  const int wr = w >> 1;
  const int wc = w & 1;
  const int row0 = by * 128;
  const int col0 = bx * 128;
  const int srow = w * 16 + (l >> 2);
  const int scol = (l & 3) * 8;
  const short* ag0 = As + (size_t)(row0 + srow) * Kd + scol;
  const short* ag1 = As + (size_t)(row0 + 64 + srow) * Kd + scol;
  const short* bg0 = Bs + (size_t)(col0 + srow) * Kd + scol;
  const short* bg1 = Bs + (size_t)(col0 + 64 + srow) * Kd + scol;
  f32x4 acc[4][4] = {};
  const int nt = Kd / 32;
  auto stage = [&](int kt, int buf) {
    int k0 = kt * 32;
    gload16(ag0 + k0, &Als[buf][w * 512]);
    gload16(ag1 + k0, &Als[buf][2048 + w * 512]);
    gload16(bg0 + k0, &Bls[buf][w * 512]);
    gload16(bg1 + k0, &Bls[buf][2048 + w * 512]);
  };
  stage(0, 0);
  __syncthreads();
  int cur = 0;
  for (int kt = 0; kt < nt; ++kt) {
    if (kt + 1 < nt) stage(kt + 1, cur ^ 1);
    bf16x8 af[4], bfr[4];
    #pragma unroll
    for (int i = 0; i < 4; i++)
      af[i] = *(const bf16x8*)&Als[cur][(wr * 64 + i * 16 + lr) * 32 + lk * 8];
    #pragma unroll
    for (int j = 0; j < 4; j++)
      bfr[j] = *(const bf16x8*)&Bls[cur][(wc * 64 + j * 16 + lr) * 32 + lk * 8];
    #pragma unroll
    for (int i = 0; i < 4; i++)
      #pragma unroll
      for (int j = 0; j < 4; j++)
        acc[i][j] = __builtin_amdgcn_mfma_f32_16x16x32_bf16(af[i], bfr[j], acc[i][j], 0, 0, 0);
    __syncthreads();
    cur ^= 1;
  }
  #pragma unroll
  for (int i = 0; i < 4; i++)
    #pragma unroll
    for (int j = 0; j < 4; j++)
      #pragma unroll
      for (int g = 0; g < 4; g++) {
        int r = row0 + wr * 64 + i * 16 + lk * 4 + g;
        int c = col0 + wc * 64 + j * 16 + lr;
        float v = acc[i][j][g];
        void* dst = Cv;
        int cc = c, ld = ldc;
        if (c >= csplit) { dst = Cv2; cc = c - csplit; ld = ldc2; }
        size_t idx = (size_t)r * ld + cc;
        if (EPI == 0)      ((float*)dst)[idx] = v;
        else if (EPI == 1) ((__hip_bfloat16*)dst)[idx] = __float2bfloat16(v);
        else if (EPI == 2) {
          float xv = v + bias[cc];
          float gl = 0.5f * xv * (1.0f + erff(xv * 0.70710678118654752f));
          ((__hip_bfloat16*)dst)[idx] = __float2bfloat16(gl);
        } else {
          float s = 1.0f / (float)((r & (TDIM - 1)) + 1);
          ((float*)dst)[idx] = v * s;
        }
      }
}

// ================= 256^2 4-phase BK=64 engine (big GEMMs) =================
// BM=BN=256, BK=64, 8 waves (2M x 4N), 2-deep buffer split into K-halves
// ([buf][kh][256][32], 128 KiB total). Per iteration (1 K-tile), 4 phases of
// {4-8 ds_read_b128 | staging share | barrier | setprio 16 MFMA setprio | barrier}:
//   ph1 (kh0, mh0): read 4B+4A, stage A-halves of t+1 (4 gloads)
//   ph2 (kh0, mh1): read 4A,    stage B-halves of t+1 (4 gloads)
//   ph3 (kh1, mh0): read 4B+4A
//   ph4 (kh1, mh1): read 4A, then vmcnt(0) (last issue was ph2 -> ~2 phases of cover)
// B-frags reused across M-half phases (24 reads/tile, not 48). Staging targets
// buf^1 (write-safe); iteration-end vmcnt+barrier gates buffer turnover.
template<int EPI>
__global__ __launch_bounds__(512, 2) void gemm_nt_256(const __hip_bfloat16* __restrict__ A,
    const __hip_bfloat16* __restrict__ B, void* __restrict__ Cv, void* __restrict__ Cv2,
    int csplit, int ldc, int ldc2, const float* __restrict__ bias, int M, int N, int Kd) {
  __shared__ __align__(16) short Als[2][2][256 * 32];   // [buf][kh] 64 KB
  __shared__ __align__(16) short Bls[2][2][256 * 32];   // 64 KB

  int nbx = gridDim.x;
  int nwg = nbx * gridDim.y;
  int bx = blockIdx.x, by = blockIdx.y;
  if ((nwg & 7) == 0) {
    int orig = by * nbx + bx;
    int cpx = nwg >> 3;
    int id = (orig & 7) * cpx + (orig >> 3);
    bx = id % nbx; by = id / nbx;
  }
  const short* As = (const short*)A;
  const short* Bs = (const short*)B;
  const int t  = threadIdx.x;      // 0..511
  const int w  = t >> 6;           // 0..7
  const int l  = t & 63;
  const int lr = l & 15;
  const int lk = l >> 4;
  const int wr = w >> 2;           // 0..1 (M half)
  const int wc = w & 3;            // 0..3 (N quarter)
  const int row0 = by * 256;
  const int col0 = bx * 256;

  // staging map (per 256x32 half-tile): thread t -> row t>>2, slot (t&3)^((row>>1)&3)
  const int srow  = t >> 2;                       // 0..127
  const int sslot = (t & 3) ^ ((srow >> 1) & 3);
  const short* agA0 = As + (size_t)(row0 + srow) * Kd + sslot * 8;
  const short* agA1 = As + (size_t)(row0 + 128 + srow) * Kd + sslot * 8;
  const short* bgB0 = Bs + (size_t)(col0 + srow) * Kd + sslot * 8;
  const short* bgB1 = Bs + (size_t)(col0 + 128 + srow) * Kd + sslot * 8;

  auto stageA = [&](int buf, int kh, int kt) {
    int k0 = kt * 64 + kh * 32;
    short* base = &Als[buf][kh][0];
    gload16(agA0 + k0, base + w * 512);
    gload16(agA1 + k0, base + 4096 + w * 512);
  };
  auto stageB = [&](int buf, int kh, int kt) {
    int k0 = kt * 64 + kh * 32;
    short* base = &Bls[buf][kh][0];
    gload16(bgB0 + k0, base + w * 512);
    gload16(bgB1 + k0, base + 4096 + w * 512);
  };

  // fragment LDS offsets within a [256][32] half (shorts), swizzled
  int aoff[8], boff[4];
  #pragma unroll
  for (int mf = 0; mf < 8; ++mf) {
    int r = wr * 128 + mf * 16 + lr;
    aoff[mf] = r * 32 + ((lk ^ ((r >> 1) & 3)) << 3);
  }
  #pragma unroll
  for (int nf = 0; nf < 4; ++nf) {
    int r = wc * 64 + nf * 16 + lr;
    boff[nf] = r * 32 + ((lk ^ ((r >> 1) & 3)) << 3);
  }

  f32x4 acc[8][4] = {};
  const int NT = Kd >> 6;   // K-tiles of 64

  // prologue: stage tile 0 into buf 0, drain, barrier
  stageA(0, 0, 0); stageA(0, 1, 0); stageB(0, 0, 0); stageB(0, 1, 0);
  asm volatile("s_waitcnt vmcnt(0)" ::: "memory");
  __builtin_amdgcn_sched_barrier(0);
  __builtin_amdgcn_s_barrier();

  for (int kt = 0; kt < NT; ++kt) {
    const int buf = kt & 1, nb = buf ^ 1;
    const short* A0 = &Als[buf][0][0];
    const short* A1 = &Als[buf][1][0];
    const short* B0 = &Bls[buf][0][0];
    const short* B1 = &Bls[buf][1][0];
    const bool st = (kt + 1 < NT);
    bf16x8 af[4], bfr[4];

    // ---- phase 1: kh0, M-half 0 ----
    #pragma unroll
    for (int i = 0; i < 4; ++i) bfr[i] = *(const bf16x8*)&B0[boff[i]];
    #pragma unroll
    for (int i = 0; i < 4; ++i) af[i]  = *(const bf16x8*)&A0[aoff[i]];
    if (st) { stageA(nb, 0, kt + 1); stageA(nb, 1, kt + 1); }
    __builtin_amdgcn_s_barrier();
    __builtin_amdgcn_s_setprio(1);
    #pragma unroll
    for (int i = 0; i < 4; ++i)
      #pragma unroll
      for (int j = 0; j < 4; ++j)
        acc[i][j] = __builtin_amdgcn_mfma_f32_16x16x32_bf16(af[i], bfr[j], acc[i][j], 0, 0, 0);
    __builtin_amdgcn_s_setprio(0);
    __builtin_amdgcn_s_barrier();

    // ---- phase 2: kh0, M-half 1 (B reused) ----
    #pragma unroll
    for (int i = 0; i < 4; ++i) af[i] = *(const bf16x8*)&A0[aoff[4 + i]];
    if (st) { stageB(nb, 0, kt + 1); stageB(nb, 1, kt + 1); }
    __builtin_amdgcn_s_barrier();
    __builtin_amdgcn_s_setprio(1);
    #pragma unroll
    for (int i = 0; i < 4; ++i)
      #pragma unroll
      for (int j = 0; j < 4; ++j)
        acc[4 + i][j] = __builtin_amdgcn_mfma_f32_16x16x32_bf16(af[i], bfr[j], acc[4 + i][j], 0, 0, 0);
    __builtin_amdgcn_s_setprio(0);
    __builtin_amdgcn_s_barrier();

    // ---- phase 3: kh1, M-half 0 ----
    #pragma unroll
    for (int i = 0; i < 4; ++i) bfr[i] = *(const bf16x8*)&B1[boff[i]];
    #pragma unroll
    for (int i = 0; i < 4; ++i) af[i]  = *(const bf16x8*)&A1[aoff[i]];
    __builtin_amdgcn_s_barrier();
    __builtin_amdgcn_s_setprio(1);
    #pragma unroll
    for (int i = 0; i < 4; ++i)
      #pragma unroll
      for (int j = 0; j < 4; ++j)
        acc[i][j] = __builtin_amdgcn_mfma_f32_16x16x32_bf16(af[i], bfr[j], acc[i][j], 0, 0, 0);
    __builtin_amdgcn_s_setprio(0);
    __builtin_amdgcn_s_barrier();

    // ---- phase 4: kh1, M-half 1 ----
    #pragma unroll
    for (int i = 0; i < 4; ++i) af[i] = *(const bf16x8*)&A1[aoff[4 + i]];
    __builtin_amdgcn_s_barrier();
    __builtin_amdgcn_s_setprio(1);
    #pragma unroll
    for (int i = 0; i < 4; ++i)
      #pragma unroll
      for (int j = 0; j < 4; ++j)
        acc[4 + i][j] = __builtin_amdgcn_mfma_f32_16x16x32_bf16(af[i], bfr[j], acc[4 + i][j], 0, 0, 0);
    __builtin_amdgcn_s_setprio(0);
    // iteration-end gate: tile kt+1 fully landed (last issue was phase 2 -> ~2 phases ago)
    asm volatile("s_waitcnt vmcnt(0)" ::: "memory");
    __builtin_amdgcn_sched_barrier(0);
    __builtin_amdgcn_s_barrier();
  }

  #pragma unroll
  for (int mf = 0; mf < 8; ++mf)
    #pragma unroll
    for (int nf = 0; nf < 4; ++nf)
      #pragma unroll
      for (int g = 0; g < 4; ++g) {
        int r = row0 + wr * 128 + mf * 16 + lk * 4 + g;
        int c = col0 + wc * 64 + nf * 16 + lr;
        float v = acc[mf][nf][g];
        void* dst = Cv;
        int cc = c, ld = ldc;
        if (c >= csplit) { dst = Cv2; cc = c - csplit; ld = ldc2; }
        size_t idx = (size_t)r * ld + cc;
        if (EPI == 0)      ((float*)dst)[idx] = v;
        else if (EPI == 1) ((__hip_bfloat16*)dst)[idx] = __float2bfloat16(v);
        else if (EPI == 2) {
          float xv = v + bias[cc];
          float gl = 0.5f * xv * (1.0f + erff(xv * 0.70710678118654752f));
          ((__hip_bfloat16*)dst)[idx] = __float2bfloat16(gl);
        } else {  // EPI == 4: divide by n_valid, f32 out
          float s = 1.0f / (float)((r & (TDIM - 1)) + 1);
          ((float*)dst)[idx] = v * s;
        }
      }
}

// ---------------- dual router: one launch covers Hf (y=0) and Hi (y=1) ----------------
__global__ __launch_bounds__(256) void router_kernel(const __hip_bfloat16* __restrict__ Hf,
    const __hip_bfloat16* __restrict__ Hi,
    const float* __restrict__ w2, const float* __restrict__ b2,
    const float* __restrict__ ebias, float* __restrict__ wgt_f, float* __restrict__ wgt_i) {
  const __hip_bfloat16* H = blockIdx.y ? Hi : Hf;
  float* wgt = blockIdx.y ? wgt_i : wgt_f;
  int wv = threadIdx.x >> 6;
  int l  = threadIdx.x & 63;
  int row = blockIdx.x * 4 + wv;
  if (row >= BT) return;
  float acc[KEXPN] = {};
  for (int i = 0; i < BDIM / 64; i++) {
    int h = i * 64 + l;
    float hv = __bfloat162float(H[(size_t)row * BDIM + h]);
    #pragma unroll
    for (int k = 0; k < KEXPN; k++) acc[k] += hv * w2[k * BDIM + h];
  }
  #pragma unroll
  for (int k = 0; k < KEXPN; k++)
    for (int off = 32; off; off >>= 1) acc[k] += __shfl_down(acc[k], off);
  if (l == 0) {
    float lg[KEXPN];
    float mx = -1e30f;
    #pragma unroll
    for (int k = 0; k < KEXPN; k++) { lg[k] = acc[k] + b2[k] + ebias[k]; mx = fmaxf(mx, lg[k]); }
    float s = 0.0f;
    #pragma unroll
    for (int k = 0; k < KEXPN; k++) { lg[k] = expf(lg[k] - mx); s += lg[k]; }
    float inv = 1.0f / s;
    #pragma unroll
    for (int k = 0; k < KEXPN; k++) wgt[(size_t)row * KEXPN + k] = lg[k] * inv;
  }
}

// ---------------- cumsum phase 1: per-chunk sums (yW is bf16) ----------------
__global__ __launch_bounds__(1024) void chunksum_kernel(const __hip_bfloat16* __restrict__ yW,
    float* __restrict__ S) {
  int j  = threadIdx.x;
  int ch = blockIdx.x;
  int b  = blockIdx.y;
  size_t base = ((size_t)b * TDIM + ch * TC) * KRC + j;
  float s = 0.0f;
  for (int t = 0; t < TC; t++) s += __bfloat162float(yW[base + (size_t)t * KRC]);
  S[((size_t)b * NCH + ch) * KRC + j] = s;
}

// ---------------- cumsum phase 2: exclusive scan of chunk sums (in place) ----------------
__global__ __launch_bounds__(1024) void scan_chunks_kernel(float* __restrict__ S) {
  int j = threadIdx.x;
  int b = blockIdx.x;
  float run = 0.0f;
  for (int ch = 0; ch < NCH; ch++) {
    size_t i = ((size_t)b * NCH + ch) * KRC + j;
    float v = S[i];
    S[i] = run;
    run += v;
  }
}

// ---------------- cumsum phase 3 + combine both branches -> Pcat (+ ext cols fused) ----------------
__global__ __launch_bounds__(1024) void combine_kernel(const __hip_bfloat16* __restrict__ yW,
    const float* __restrict__ S, const __hip_bfloat16* __restrict__ xV,
    const float* __restrict__ wf, const float* __restrict__ wi,
    const float* __restrict__ alphaPtr, __hip_bfloat16* __restrict__ P) {
  int j  = threadIdx.x;
  int ch = blockIdx.x;
  int b  = blockIdx.y;
  float alpha = alphaPtr[0];
  float scale = (j < KR) ? 1.0f : alpha;
  const float* wgt = (j < KR) ? wf : wi;
  int k = (j & (KR - 1)) >> 6;
  int pcol = (j < KR) ? j : j + 128;
  float run = S[((size_t)b * NCH + ch) * KRC + j];
  for (int t0 = 0; t0 < TC; t0++) {
    size_t row = (size_t)b * TDIM + ch * TC + t0;
    run += __bfloat162float(yW[row * KRC + j]);
    float p = __bfloat162float(xV[row * KRC + j]) * run * wgt[row * KEXPN + k] * scale;
    P[row * PW + pcol] = __float2bfloat16(p);
  }
  // fused ext-column fill: threads 0..255 write the 2x128 extension columns
  if (j < 256) {
    int half = j >> 7, jj = j & 127;
    int col = half ? (KC + KR + jj) : (KR + jj);
    const float* wg = half ? wi : wf;
    float sc = half ? alpha : 1.0f;
    for (int t0 = 0; t0 < TC; t0++) {
      size_t row = (size_t)b * TDIM + ch * TC + t0;
      float v = (jj < KEXPN) ? wg[row * KEXPN + jj] * sc : 0.0f;
      P[row * PW + col] = __float2bfloat16(v);
    }
  }
}

// ---------------- sentinel ----------------
__global__ __launch_bounds__(256) void fill_kernel(float* __restrict__ out, long n, float val) {
  long id = (long)blockIdx.x * 256 + threadIdx.x;
  if (id < n) out[id] = val;
}

extern "C" void kernel_launch(void* const* d_in, const int* in_sizes, int n_in,
                              void* d_out, int out_size, void* d_ws, size_t ws_size,
                              hipStream_t stream) {
  const float* x        = (const float*)d_in[0];
  const float* W_Q      = (const float*)d_in[1];
  const float* W_K      = (const float*)d_in[2];
  const float* W_O      = (const float*)d_in[3];
  const float* W_inv    = (const float*)d_in[4];
  const float* V_fwd    = (const float*)d_in[5];
  const float* W_fwd    = (const float*)d_in[6];
  const float* U_fwd    = (const float*)d_in[7];
  const float* b_fwd    = (const float*)d_in[8];
  const float* V_inv    = (const float*)d_in[9];
  const float* W_inv_e  = (const float*)d_in[10];
  const float* U_inv    = (const float*)d_in[11];
  const float* b_inv    = (const float*)d_in[12];
  const float* rw1      = (const float*)d_in[13];
  const float* rb1      = (const float*)d_in[14];
  const float* rw2      = (const float*)d_in[15];
  const float* rb2      = (const float*)d_in[16];
  const float* alphaPtr = (const float*)d_in[17];
  const float* ebias    = (const float*)d_in[18];

  char* ws = (char*)d_ws;
  size_t off = 0;
  auto alloc = [&](size_t sz) -> void* {
    void* p = ws + off;
    off += (sz + 255) & ~(size_t)255;
    return p;
  };

  void* wqk   = alloc((size_t)2 * BDIM * BDIM * 2); // [W_Q rows | W_K rows]
  void* w1p   = alloc((size_t)2 * BDIM * BDIM * 2); // [w1 rows | w1i rows]
  void* wo    = alloc((size_t)BDIM * BDIM * 2);
  void* winvT = alloc((size_t)BDIM * BDIM * 2);
  void* vmq   = alloc((size_t)KRC * BDIM * 2);      // rows 0-511 vm_f, 512-1023 Gq
  void* wmG   = alloc((size_t)KRC * BDIM * 2);      // rows 0-511 wm_f, 512-1023 Gk
  void* vm_ie = alloc((size_t)KR * BDIM * 2);
  void* vm_i  = alloc((size_t)KR * BDIM * 2);
  void* utTf  = alloc((size_t)KC * BDIM * 2);
  void* utTi  = alloc((size_t)KC * BDIM * 2);
  void* Mcat  = alloc((size_t)BDIM * PW * 2);
  void* wgt_f = alloc((size_t)BT * KEXPN * 4);
  void* wgt_i = alloc((size_t)BT * KEXPN * 4);
  void* S     = alloc((size_t)4 * NCH * KRC * 4);
  void* s_Q   = alloc((size_t)BT * BDIM * 2);
  void* s_K   = alloc((size_t)BT * BDIM * 2);
  void* s_x   = alloc((size_t)BT * BDIM * 2);
  void* s_yW  = alloc((size_t)BT * KRC * 2);        // bf16: Hi (early), then yWcat
  void* Hf    = s_x;
  void* Hi    = s_yW;
  void* xVcat = s_x;
  void* Pcat  = s_Q;

  if (off > ws_size) {
    fill_kernel<<<dim3((unsigned)((out_size + 255) / 256)), 256, 0, stream>>>(
        (float*)d_out, (long)out_size, (float)(off >> 20));
    return;
  }

  __hip_bfloat16* wq  = (__hip_bfloat16*)wqk;
  __hip_bfloat16* wk  = wq + (size_t)BDIM * BDIM;
  __hip_bfloat16* w1  = (__hip_bfloat16*)w1p;
  __hip_bfloat16* w1i = w1 + (size_t)BDIM * BDIM;
  __hip_bfloat16* Gq  = (__hip_bfloat16*)vmq + (size_t)KR * BDIM;
  __hip_bfloat16* Gk  = (__hip_bfloat16*)wmG + (size_t)KR * BDIM;

  auto cvt = [&](const float* in, void* out, long n) {
    long n4 = n / 4;
    cvt_bf16_kernel<<<dim3((unsigned)((n4 + 255) / 256)), dim3(256), 0, stream>>>(
        in, (__hip_bfloat16*)out, n4);
  };
  // 128^2 engine (folds)
  auto gemm2s = [&](const void* A, const void* Bm, void* C, void* C2, int csplit,
                    int ldc, int ldc2, int M, int N, int Kd, int epi, const float* bias) {
    dim3 g(N / 128, M / 128);
    if (epi == 0)      gemm_nt<0><<<g, 256, 0, stream>>>((const __hip_bfloat16*)A, (const __hip_bfloat16*)Bm, C, C2, csplit, ldc, ldc2, bias, M, N, Kd);
    else if (epi == 1) gemm_nt<1><<<g, 256, 0, stream>>>((const __hip_bfloat16*)A, (const __hip_bfloat16*)Bm, C, C2, csplit, ldc, ldc2, bias, M, N, Kd);
    else if (epi == 2) gemm_nt<2><<<g, 256, 0, stream>>>((const __hip_bfloat16*)A, (const __hip_bfloat16*)Bm, C, C2, csplit, ldc, ldc2, bias, M, N, Kd);
    else               gemm_nt<4><<<g, 256, 0, stream>>>((const __hip_bfloat16*)A, (const __hip_bfloat16*)Bm, C, C2, csplit, ldc, ldc2, bias, M, N, Kd);
  };
  auto gemms = [&](const void* A, const void* Bm, void* C, int M, int N, int Kd,
                   int epi, const float* bias) {
    gemm2s(A, Bm, C, C, N, N, N, M, N, Kd, epi, bias);
  };
  // 256^2 BK=64 engine (big GEMMs; M,N multiples of 256, K multiple of 64)
  auto gemm2b = [&](const void* A, const void* Bm, void* C, void* C2, int csplit,
                    int ldc, int ldc2, int M, int N, int Kd, int epi, const float* bias) {
    dim3 g(N / 256, M / 256);
    if (epi == 0)      gemm_nt_256<0><<<g, 512, 0, stream>>>((const __hip_bfloat16*)A, (const __hip_bfloat16*)Bm, C, C2, csplit, ldc, ldc2, bias, M, N, Kd);
    else if (epi == 1) gemm_nt_256<1><<<g, 512, 0, stream>>>((const __hip_bfloat16*)A, (const __hip_bfloat16*)Bm, C, C2, csplit, ldc, ldc2, bias, M, N, Kd);
    else if (epi == 2) gemm_nt_256<2><<<g, 512, 0, stream>>>((const __hip_bfloat16*)A, (const __hip_bfloat16*)Bm, C, C2, csplit, ldc, ldc2, bias, M, N, Kd);
    else               gemm_nt_256<4><<<g, 512, 0, stream>>>((const __hip_bfloat16*)A, (const __hip_bfloat16*)Bm, C, C2, csplit, ldc, ldc2, bias, M, N, Kd);
  };
  auto gemmb = [&](const void* A, const void* Bm, void* C, int M, int N, int Kd,
                   int epi, const float* bias) {
    gemm2b(A, Bm, C, C, N, N, N, M, N, Kd, epi, bias);
  };

  // ---- conversions & packing ----
  cvt(x,   s_x, (long)BT * BDIM);
  cvt(W_Q, wq,  (long)BDIM * BDIM);
  cvt(W_K, wk,  (long)BDIM * BDIM);
  cvt(W_O, wo,  (long)BDIM * BDIM);
  cvt(rw1, w1,  (long)BDIM * BDIM);
  {
    dim3 gt((BDIM * BDIM + 255) / 256);
    transpose_pack_kernel<<<gt, 256, 0, stream>>>(W_inv, (__hip_bfloat16*)winvT);
    dim3 g((KR * BDIM + 255) / 256);
    pack_vmat_kernel<<<g, 256, 0, stream>>>(V_fwd,   (__hip_bfloat16*)vmq);
    pack_vmat_kernel<<<g, 256, 0, stream>>>(W_fwd,   (__hip_bfloat16*)wmG);
    pack_vmat_kernel<<<g, 256, 0, stream>>>(W_inv_e, (__hip_bfloat16*)vm_ie);
    pack_vmat_kernel<<<g, 256, 0, stream>>>(V_inv,   (__hip_bfloat16*)vm_i);
    dim3 gu((KC * BDIM + 255) / 256);
    pack_utT_kernel<<<gu, 256, 0, stream>>>(U_fwd, b_fwd, (__hip_bfloat16*)utTf);
    pack_utT_kernel<<<gu, 256, 0, stream>>>(U_inv, b_inv, (__hip_bfloat16*)utTi);
  }

  // ---- weight folds (128^2 engine) ----
  gemms(w1,    winvT, w1i, BDIM, BDIM, BDIM, 1, nullptr);
  gemms(vm_ie, winvT, Gq,  KR,   BDIM, BDIM, 1, nullptr);
  gemms(vm_i,  winvT, Gk,  KR,   BDIM, BDIM, 1, nullptr);
  gemm2s(wo, utTf, Mcat, Mcat, KC, PW, PW, BDIM, KC, BDIM, 1, nullptr);
  gemm2s(wo, utTi, (__hip_bfloat16*)Mcat + KC, (__hip_bfloat16*)Mcat + KC,
         KC, PW, PW, BDIM, KC, BDIM, 1, nullptr);

  // ---- fused Q|K projection ----
  gemm2b(s_x, wqk, s_Q, s_K, BDIM, BDIM, BDIM, BT, 2 * BDIM, BDIM, 1, nullptr);

  // ---- fused H + dual router ----
  gemm2b(s_Q, w1p, Hf, Hi, BDIM, BDIM, BDIM, BT, 2 * BDIM, BDIM, 2, rb1);
  router_kernel<<<dim3(BT / 4, 2), 256, 0, stream>>>((const __hip_bfloat16*)Hf,
      (const __hip_bfloat16*)Hi, rw2, rb2, ebias, (float*)wgt_f, (float*)wgt_i);

  // ---- fused branch GEMMs (xVcat bf16 overlays Hf; yWcat bf16) ----
  gemmb(s_Q, vmq, xVcat, BT, KRC, BDIM, 1, nullptr);
  gemmb(s_K, wmG, s_yW,  BT, KRC, BDIM, 1, nullptr);

  // ---- causal cumsum + combine into Pcat (ext cols fused) ----
  dim3 gch(NCH, 4);
  chunksum_kernel<<<gch, 1024, 0, stream>>>((const __hip_bfloat16*)s_yW, (float*)S);
  scan_chunks_kernel<<<dim3(4), 1024, 0, stream>>>((float*)S);
  combine_kernel<<<gch, 1024, 0, stream>>>((const __hip_bfloat16*)s_yW, (const float*)S,
      (const __hip_bfloat16*)xVcat, (const float*)wgt_f, (const float*)wgt_i,
      alphaPtr, (__hip_bfloat16*)Pcat);

  // ---- single output GEMM: out = diag(1/n) * Pcat @ Mcat^T ----
  gemmb(Pcat, Mcat, d_out, BT, BDIM, PW, 4, nullptr);
}